// Round 2
// baseline (2147.934 us; speedup 1.0000x reference)
//
#include <hip/hip_runtime.h>
#include <cstdint>

typedef _Float16 half_t;
typedef _Float16 half2_t __attribute__((ext_vector_type(2)));
typedef _Float16 h8_t __attribute__((ext_vector_type(8)));
typedef float f4_t __attribute__((ext_vector_type(4)));
typedef unsigned int uint32;

static constexpr int B_ = 64, T_ = 1024;

#define DEV __device__ __forceinline__

DEV float fdot2f(half2_t a, half2_t b, float c) {
#if __has_builtin(__builtin_amdgcn_fdot2)
  return __builtin_amdgcn_fdot2(a, b, c, false);
#else
  return fmaf((float)a.x, (float)b.x, fmaf((float)a.y, (float)b.y, c));
#endif
}

DEV float fast_rcp(float x) { return __builtin_amdgcn_rcpf(x); }
DEV float sigmf(float x) { return fast_rcp(1.f + __expf(-x)); }
DEV float tanhf_(float x) { return 1.f - 2.f * fast_rcp(1.f + __expf(2.f * x)); }
DEV uint32 pack2(float a, float b) {
  half2_t h; h.x = (half_t)a; h.y = (half_t)b;
  return __builtin_bit_cast(uint32, h);
}

DEV void gload_lds16(const void* g, void* l) {
  __builtin_amdgcn_global_load_lds(
      (const __attribute__((address_space(1))) uint32*)g,
      (__attribute__((address_space(3))) uint32*)l, 16, 0, 0);
}

// ---------------- weight packing (f32 -> packed f16) ----------------
__global__ __launch_bounds__(256) void pack_w(
    const float* __restrict__ w_ih_f, const float* __restrict__ w_ih_b,
    const float* __restrict__ mu_w, const float* __restrict__ lv_w,
    const float* __restrict__ sw_w1,
    const float* __restrict__ w_hh_f, const float* __restrict__ w_hh_b,
    const float* __restrict__ mu_b, const float* __restrict__ lv_b,
    const float* __restrict__ sw_b1,
    uint32* __restrict__ wihf, uint32* __restrict__ wihb,
    uint32* __restrict__ wce, uint32* __restrict__ wchf, uint32* __restrict__ wchb,
    uint32* __restrict__ whh, uint32* __restrict__ w1z, float* __restrict__ biasc) {
  int id = blockIdx.x * 256 + threadIdx.x;
  if (id < 98304) { wihf[id] = pack2(w_ih_f[2*id], w_ih_f[2*id+1]); return; }
  id -= 98304;
  if (id < 98304) { wihb[id] = pack2(w_ih_b[2*id], w_ih_b[2*id+1]); return; }
  id -= 98304;
  if (id < 32768) {  // wce (256x256): rows [mu:0|lv:0|w1_e]
    int n = id >> 7, c0 = (id & 127) * 2;
    float v0 = 0.f, v1 = 0.f;
    if (n >= 128) { const float* p = sw_w1 + (n - 128) * 832 + c0; v0 = p[0]; v1 = p[1]; }
    wce[id] = pack2(v0, v1); return;
  }
  id -= 32768;
  if (id < 32768) {  // wchf (256x256): h_f columns of [mu_w|lv_w|w1_h]
    int n = id >> 7, c0 = (id & 127) * 2;
    const float* p = (n < 64)  ? mu_w + n * 512 + c0
                   : (n < 128) ? lv_w + (n - 64) * 512 + c0
                               : sw_w1 + (n - 128) * 832 + 256 + c0;
    wchf[id] = pack2(p[0], p[1]); return;
  }
  id -= 32768;
  if (id < 32768) {  // wchb (256x256): h_b columns
    int n = id >> 7, c0 = (id & 127) * 2;
    const float* p = (n < 64)  ? mu_w + n * 512 + 256 + c0
                   : (n < 128) ? lv_w + (n - 64) * 512 + 256 + c0
                               : sw_w1 + (n - 128) * 832 + 512 + c0;
    wchb[id] = pack2(p[0], p[1]); return;
  }
  id -= 32768;
  if (id < 196608) {  // w_hh per-thread-register layout, 2 dirs
    int d = id / 98304, q = id % 98304;
    int dw = q / 512, t2 = q % 512;
    int r = t2 >> 2, pp = t2 & 3;
    int i = dw / 96, g = (dw % 96) / 32, dd = dw % 32;
    int row = 256 * g + 2 * r + i;
    int k0 = 64 * pp + 2 * dd;
    const float* w = d ? w_hh_b : w_hh_f;
    whh[id] = pack2(w[row * 256 + k0], w[row * 256 + k0 + 1]);
    return;
  }
  id -= 196608;
  if (id < 4096) {  // w1_z = sw_w1[:, 768:832], per-thread layout
    int j = id / 128, k2 = id % 128;
    w1z[id] = pack2(sw_w1[k2 * 832 + 768 + 2 * j], sw_w1[k2 * 832 + 768 + 2 * j + 1]);
    return;
  }
  id -= 4096;
  if (id < 256) {
    biasc[id] = (id < 64) ? mu_b[id] : (id < 128) ? lv_b[id - 64] : sw_b1[id - 128];
  }
}

// ---------------- GEMM: C(MxN) = A(MxK) * B(N,K)^T [+bias] [+=C] ----------------
// 128x128 tile, BK=64, 4 waves. A either f32 (reg-stage+cvt) or f16 (global_load_lds).
template <int AF32, int ACC>
__global__ __launch_bounds__(256) void gemm_t(
    const void* __restrict__ Ap, int lda,
    const half_t* __restrict__ Bw,  // (N,K) f16 row-major
    const float* __restrict__ bias,
    half_t* __restrict__ C, int ldc, int K) {
  __shared__ __align__(16) half_t smem[16384];
  half_t* As = smem;         // [128][64]
  half_t* Bs = smem + 8192;  // [128][64]
  const int tid = threadIdx.x;
  const int lane = tid & 63, w = tid >> 6;
  const int n0 = blockIdx.x * 128, m0 = blockIdx.y * 128;
  const int r8 = lane >> 3, c8 = lane & 7;
  f4_t acc[4][4];
  f4_t zero = {0.f, 0.f, 0.f, 0.f};
#pragma unroll
  for (int i = 0; i < 4; ++i)
#pragma unroll
    for (int j = 0; j < 4; ++j) acc[i][j] = zero;
  const int wm = (w >> 1) * 64, wn = (w & 1) * 64;
  for (int ks = 0; ks < K; ks += 64) {
    if constexpr (AF32) {
      const float* Af = (const float*)Ap;
#pragma unroll
      for (int it = 0; it < 4; ++it) {
        int c = it * 256 + tid;             // 1024 chunks of 8 halves
        int row = c >> 3, coff = (c & 7) * 8;
        const float* ap = Af + (size_t)(m0 + row) * lda + ks + coff;
        float4 v0 = *(const float4*)ap;
        float4 v1 = *(const float4*)(ap + 4);
        uint4 u;
        u.x = pack2(v0.x, v0.y); u.y = pack2(v0.z, v0.w);
        u.z = pack2(v1.x, v1.y); u.w = pack2(v1.z, v1.w);
        *(uint4*)&As[(size_t)c * 8] = u;
      }
    } else {
      const half_t* Af = (const half_t*)Ap;
#pragma unroll
      for (int c = 0; c < 4; ++c) {
        int row = w * 32 + c * 8 + r8;
        gload_lds16(Af + (size_t)(m0 + row) * lda + ks + c8 * 8, As + (w * 4 + c) * 512);
      }
    }
#pragma unroll
    for (int c = 0; c < 4; ++c) {
      int row = w * 32 + c * 8 + r8;
      gload_lds16(Bw + (size_t)(n0 + row) * K + ks + c8 * 8, Bs + (w * 4 + c) * 512);
    }
    __syncthreads();
#pragma unroll
    for (int kk = 0; kk < 2; ++kk) {
      h8_t af[4], bf[4];
      const int ko = kk * 32 + (lane >> 4) * 8;
#pragma unroll
      for (int i = 0; i < 4; ++i) af[i] = *(const h8_t*)&As[(wm + i * 16 + (lane & 15)) * 64 + ko];
#pragma unroll
      for (int j = 0; j < 4; ++j) bf[j] = *(const h8_t*)&Bs[(wn + j * 16 + (lane & 15)) * 64 + ko];
#pragma unroll
      for (int i = 0; i < 4; ++i)
#pragma unroll
        for (int j = 0; j < 4; ++j)
          acc[i][j] = __builtin_amdgcn_mfma_f32_16x16x32_f16(af[i], bf[j], acc[i][j], 0, 0, 0);
    }
    __syncthreads();
  }
  // epilogue: bias + f16 cvt into LDS bounce, then coalesced 16B stores (+acc)
  const int cl4 = lane & 15, rl4 = lane >> 4;
#pragma unroll
  for (int j = 0; j < 4; ++j) {
    float bj = bias ? bias[n0 + wn + j * 16 + cl4] : 0.f;
#pragma unroll
    for (int i = 0; i < 4; ++i)
#pragma unroll
      for (int q = 0; q < 4; ++q) {
        int rl = wm + i * 16 + rl4 * 4 + q;
        int cc = wn + j * 16 + cl4;
        smem[rl * 128 + cc] = (half_t)(acc[i][j][q] + bj);
      }
  }
  __syncthreads();
#pragma unroll
  for (int it = 0; it < 8; ++it) {
    int idx = it * 256 + tid;
    int row = idx >> 4, colc = idx & 15;
    uint4 v = *(const uint4*)&smem[row * 128 + colc * 8];
    half_t* cp = C + (size_t)(m0 + row) * ldc + n0 + colc * 8;
    if constexpr (ACC) {
      uint4 o = *(const uint4*)cp;
      h8_t vv = __builtin_bit_cast(h8_t, v) + __builtin_bit_cast(h8_t, o);
      v = __builtin_bit_cast(uint4, vv);
    }
    *(uint4*)cp = v;
  }
}

// ---------------- GRU recurrence: weight-stationary in VGPRs ----------------
// 128 WGs = (b, dir); 512 threads = 128 row-groups (2 hidden units) x 4 K-slices.
// Writes h_t IN PLACE into xp row t, dwords [0,128) (the consumed xr slot).
__global__ __launch_bounds__(512, 2) void gru_rec(
    uint32* __restrict__ xp,         // [2][B][T][384] dwords (f16 pairs)
    const uint32* __restrict__ whh,  // [2][192][512] packed half2
    const float* __restrict__ bhh_f, const float* __restrict__ bhh_b) {
  const int wg = blockIdx.x;
  const int d = wg >> 6, b = wg & 63;
  const int tid = threadIdx.x;
  const int r = tid >> 2, p = tid & 3;
  __shared__ uint32 hb[2][128];
  if (tid < 128) { hb[0][tid] = 0; hb[1][tid] = 0; }
  half2_t wv[192];
  const uint32* wp = whh + (size_t)d * 98304 + tid;
#pragma unroll
  for (int j = 0; j < 192; ++j) wv[j] = __builtin_bit_cast(half2_t, wp[j * 512]);
  const float* bhh = d ? bhh_b : bhh_f;
  float bh[6];
#pragma unroll
  for (int g = 0; g < 3; ++g) { bh[g] = bhh[256 * g + 2 * r]; bh[3 + g] = bhh[256 * g + 2 * r + 1]; }
  uint32* xpu = xp + ((size_t)d * B_ + b) * T_ * 384;
  float h0 = 0.f, h1 = 0.f;
  const int dt = d ? -1 : 1;
  int t = d ? (T_ - 1) : 0;
  uint32 xr_n = 0, xz_n = 0, xn_n = 0;
  if (p == 0) {
    const uint32* rowp = xpu + (size_t)t * 384;
    xr_n = rowp[r]; xz_n = rowp[128 + r]; xn_n = rowp[256 + r];
  }
  __syncthreads();
  for (int step = 0; step < T_; ++step) {
    const int cur = step & 1;
    const uint32 xr = xr_n, xz = xz_n, xn = xn_n;
    const int tn = (step < T_ - 1) ? (t + dt) : t;
    if (p == 0) {  // prefetch next timestep's xp
      const uint32* rowp = xpu + (size_t)tn * 384;
      xr_n = rowp[r]; xz_n = rowp[128 + r]; xn_n = rowp[256 + r];
    }
    float a00 = 0, a01 = 0, a02 = 0, a10 = 0, a11 = 0, a12 = 0;
#pragma unroll
    for (int c = 0; c < 4; ++c) {
      half2_t hv[8];
#pragma unroll
      for (int e = 0; e < 8; ++e) hv[e] = __builtin_bit_cast(half2_t, hb[cur][p * 32 + c * 8 + e]);
#pragma unroll
      for (int e = 0; e < 8; ++e) {
        const int dd = c * 8 + e;
        a00 = fdot2f(wv[dd], hv[e], a00);
        a01 = fdot2f(wv[dd + 32], hv[e], a01);
        a02 = fdot2f(wv[dd + 64], hv[e], a02);
        a10 = fdot2f(wv[dd + 96], hv[e], a10);
        a11 = fdot2f(wv[dd + 128], hv[e], a11);
        a12 = fdot2f(wv[dd + 160], hv[e], a12);
      }
    }
    a00 += __shfl_xor(a00, 1); a00 += __shfl_xor(a00, 2);
    a01 += __shfl_xor(a01, 1); a01 += __shfl_xor(a01, 2);
    a02 += __shfl_xor(a02, 1); a02 += __shfl_xor(a02, 2);
    a10 += __shfl_xor(a10, 1); a10 += __shfl_xor(a10, 2);
    a11 += __shfl_xor(a11, 1); a11 += __shfl_xor(a11, 2);
    a12 += __shfl_xor(a12, 1); a12 += __shfl_xor(a12, 2);
    if (p == 0) {
      half2_t xrv = __builtin_bit_cast(half2_t, xr);
      half2_t xzv = __builtin_bit_cast(half2_t, xz);
      half2_t xnv = __builtin_bit_cast(half2_t, xn);
      float r0 = sigmf((float)xrv.x + a00 + bh[0]);
      float z0 = sigmf((float)xzv.x + a01 + bh[1]);
      float n0 = tanhf_((float)xnv.x + r0 * (a02 + bh[2]));
      h0 = (1.f - z0) * n0 + z0 * h0;
      float r1 = sigmf((float)xrv.y + a10 + bh[3]);
      float z1 = sigmf((float)xzv.y + a11 + bh[4]);
      float n1 = tanhf_((float)xnv.y + r1 * (a12 + bh[5]));
      h1 = (1.f - z1) * n1 + z1 * h1;
      uint32 ph = pack2(h0, h1);
      hb[cur ^ 1][r] = ph;
      xpu[(size_t)t * 384 + r] = ph;  // in-place h store (xr slot is dead)
    }
    __syncthreads();
    t = tn;
  }
}

// ---------------- z_tilde + KL partials ----------------
__global__ __launch_bounds__(256) void zkl(const half_t* __restrict__ hp,  // stride 768
                                           const float* __restrict__ eps,
                                           float* __restrict__ ztil,
                                           float* __restrict__ klp) {
  const int blk = blockIdx.x, tid = threadIdx.x;
  const size_t bt = (size_t)blk * 4 + (tid >> 6);
  const int j = tid & 63;
  float mu = (float)hp[bt * 768 + j];
  float lv = (float)hp[bt * 768 + 64 + j];
  float ev = eps[bt * 64 + j];
  ztil[bt * 64 + j] = mu + __expf(0.5f * lv) * ev;
  float term = 1.f + lv - mu * mu - __expf(lv);
#pragma unroll
  for (int s = 1; s < 64; s <<= 1) term += __shfl_xor(term, s);
  __shared__ float red[4];
  if ((tid & 63) == 0) red[tid >> 6] = term;
  __syncthreads();
  if (tid == 0) klp[blk] = red[0] + red[1] + red[2] + red[3];
}

__global__ __launch_bounds__(256) void klred(const float* __restrict__ klp,
                                             float* __restrict__ out) {
  const int tid = threadIdx.x;
  float s = 0.f;
  for (int i = tid; i < 16384; i += 256) s += klp[i];
#pragma unroll
  for (int st = 1; st < 64; st <<= 1) s += __shfl_xor(s, st);
  __shared__ float red[4];
  if ((tid & 63) == 0) red[tid >> 6] = s;
  __syncthreads();
  if (tid == 0) out[0] = (red[0] + red[1] + red[2] + red[3]) * (-0.5f / 65536.f);
}

// ---------------- sequential z-scan (per batch element) ----------------
__global__ __launch_bounds__(128) void z_scan(
    const half_t* __restrict__ hp,  // pre at col offset 128, stride 768
    const float* __restrict__ zt_arr,
    const uint32* __restrict__ w1z,
    const float* __restrict__ sw_w2, const float* __restrict__ sw_b2,
    float* __restrict__ z_out, float* __restrict__ beta_out) {
  const int b = blockIdx.x;
  const int k = threadIdx.x;
  const int w = k >> 6, lane = k & 63;
  half2_t wz[32];
#pragma unroll
  for (int j = 0; j < 32; ++j) wz[j] = __builtin_bit_cast(half2_t, w1z[j * 128 + k]);
  const float w2k = sw_w2[k];
  const float b2 = sw_b2[0];
  __shared__ uint32 zb[2][32];
  __shared__ float sred[2];
  if (k < 32) zb[0][k] = 0;
  __syncthreads();
  float zf = 0.f;
  const size_t bt0 = (size_t)b * T_;
  float pre_n = (float)hp[bt0 * 768 + 128 + k];
  float ztn = (k < 64) ? zt_arr[bt0 * 64 + k] : 0.f;
  for (int t = 0; t < T_; ++t) {
    const int cur = t & 1;
    const float pre = pre_n, zt = ztn;
    half2_t zr[32];
#pragma unroll
    for (int j = 0; j < 32; ++j) zr[j] = __builtin_bit_cast(half2_t, zb[cur][j]);
    const int tn = (t < T_ - 1) ? t + 1 : t;
    pre_n = (float)hp[(bt0 + tn) * 768 + 128 + k];
    if (k < 64) ztn = zt_arr[(bt0 + tn) * 64 + k];
    float a0 = 0, a1 = 0, a2 = 0, a3 = 0;
#pragma unroll
    for (int j = 0; j < 32; j += 4) {
      a0 = fdot2f(wz[j], zr[j], a0);
      a1 = fdot2f(wz[j + 1], zr[j + 1], a1);
      a2 = fdot2f(wz[j + 2], zr[j + 2], a2);
      a3 = fdot2f(wz[j + 3], zr[j + 3], a3);
    }
    float hid = fmaxf(pre + ((a0 + a1) + (a2 + a3)), 0.f);
    float v = hid * w2k;
#pragma unroll
    for (int s = 1; s < 64; s <<= 1) v += __shfl_xor(v, s);
    if (lane == 0) sred[w] = v;
    __syncthreads();
    const float beta = sigmf(sred[0] + sred[1] + b2);
    if (k == 0) beta_out[bt0 + t] = beta;
    if (k < 64) {
      zf = beta * zt + (1.f - beta) * zf;
      z_out[(bt0 + t) * 64 + k] = zf;
      float zo = __shfl_xor(zf, 1);
      if ((k & 1) == 0) zb[cur ^ 1][k >> 1] = pack2(zf, zo);
    }
    __syncthreads();
  }
}

extern "C" void kernel_launch(void* const* d_in, const int* in_sizes, int n_in,
                              void* d_out, int out_size, void* d_ws, size_t ws_size,
                              hipStream_t stream) {
  (void)in_sizes; (void)n_in; (void)out_size;
  const float* e_seq  = (const float*)d_in[0];
  const float* eps    = (const float*)d_in[1];
  const float* w_ih_f = (const float*)d_in[2];
  const float* w_hh_f = (const float*)d_in[3];
  const float* b_ih_f = (const float*)d_in[4];
  const float* b_hh_f = (const float*)d_in[5];
  const float* w_ih_b = (const float*)d_in[6];
  const float* w_hh_b = (const float*)d_in[7];
  const float* b_ih_b = (const float*)d_in[8];
  const float* b_hh_b = (const float*)d_in[9];
  const float* mu_w   = (const float*)d_in[10];
  const float* mu_b   = (const float*)d_in[11];
  const float* lv_w   = (const float*)d_in[12];
  const float* lv_b   = (const float*)d_in[13];
  const float* sw_w1  = (const float*)d_in[14];
  const float* sw_b1  = (const float*)d_in[15];
  const float* sw_w2  = (const float*)d_in[16];
  const float* sw_b2  = (const float*)d_in[17];

  // workspace layout (total 203,310,080 B):
  //   [0, 100663296)              xpf [B][T][768] f16 -> h_f in cols[0,256), heads in cols[512,768)
  //   [100663296, 201326592)      xpb [B][T][768] f16 -> h_b in cols[0,256); later ztil+klp alias
  //   [201326592, 203310080)      packed weights
  const size_t NEED = 203310080;
  if (ws_size < NEED) return;  // diagnostic guard: clean absmax-fail instead of crash
  char* ws = (char*)d_ws;
  half_t* xpf = (half_t*)ws;
  half_t* xpb = (half_t*)(ws + 100663296);
  half_t* hp  = xpf + 512;                                  // heads, ldc/stride 768
  float*  ztil = (float*)(ws + 100663296);                  // alias xpb (dead after pass3)
  float*  klp  = (float*)(ws + 100663296 + 16777216);
  char* wr = ws + 201326592;
  uint32* wihf  = (uint32*)(wr);
  uint32* wihb  = (uint32*)(wr + 393216);
  uint32* wce   = (uint32*)(wr + 786432);
  uint32* wchf  = (uint32*)(wr + 917504);
  uint32* wchb  = (uint32*)(wr + 1048576);
  uint32* whhp  = (uint32*)(wr + 1179648);
  uint32* w1zp  = (uint32*)(wr + 1966080);
  float*  biasc = (float*)(wr + 1982464);

  pack_w<<<1937, 256, 0, stream>>>(w_ih_f, w_ih_b, mu_w, lv_w, sw_w1, w_hh_f, w_hh_b,
                                   mu_b, lv_b, sw_b1,
                                   wihf, wihb, wce, wchf, wchb, whhp, w1zp, biasc);
  gemm_t<1, 0><<<dim3(6, 512), 256, 0, stream>>>(e_seq, 256, (const half_t*)wihf, b_ih_f, xpf, 768, 256);
  gemm_t<1, 0><<<dim3(6, 512), 256, 0, stream>>>(e_seq, 256, (const half_t*)wihb, b_ih_b, xpb, 768, 256);
  gru_rec<<<128, 512, 0, stream>>>((uint32*)ws, whhp, b_hh_f, b_hh_b);
  gemm_t<1, 0><<<dim3(2, 512), 256, 0, stream>>>(e_seq, 256, (const half_t*)wce, biasc, hp, 768, 256);
  gemm_t<0, 1><<<dim3(2, 512), 256, 0, stream>>>(xpf, 768, (const half_t*)wchf, nullptr, hp, 768, 256);
  gemm_t<0, 1><<<dim3(2, 512), 256, 0, stream>>>(xpb, 768, (const half_t*)wchb, nullptr, hp, 768, 256);
  zkl<<<16384, 256, 0, stream>>>(hp, eps, ztil, klp);
  klred<<<1, 256, 0, stream>>>(klp, (float*)d_out + 4194304);
  z_scan<<<64, 128, 0, stream>>>(hp, ztil, w1zp, sw_w2, sw_b2, (float*)d_out, (float*)d_out + 4194305);
}

// Round 3
// 2105.307 us; speedup vs baseline: 1.0202x; 1.0202x over previous
//
#include <hip/hip_runtime.h>
#include <cstdint>

typedef _Float16 half_t;
typedef _Float16 half2_t __attribute__((ext_vector_type(2)));
typedef _Float16 h8_t __attribute__((ext_vector_type(8)));
typedef float f4_t __attribute__((ext_vector_type(4)));
typedef unsigned int uint32;

static constexpr int B_ = 64, T_ = 1024;

#define DEV __device__ __forceinline__

DEV float fdot2f(half2_t a, half2_t b, float c) {
#if __has_builtin(__builtin_amdgcn_fdot2)
  return __builtin_amdgcn_fdot2(a, b, c, false);
#else
  return fmaf((float)a.x, (float)b.x, fmaf((float)a.y, (float)b.y, c));
#endif
}

DEV float fast_rcp(float x) { return __builtin_amdgcn_rcpf(x); }
DEV float sigmf(float x) { return fast_rcp(1.f + __expf(-x)); }
DEV float tanhf_(float x) { return 1.f - 2.f * fast_rcp(1.f + __expf(2.f * x)); }
DEV uint32 pack2(float a, float b) {
  half2_t h; h.x = (half_t)a; h.y = (half_t)b;
  return __builtin_bit_cast(uint32, h);
}
DEV half2_t bch2(uint32 u) { return __builtin_bit_cast(half2_t, u); }

DEV void gload_lds16(const void* g, void* l) {
  __builtin_amdgcn_global_load_lds(
      (const __attribute__((address_space(1))) uint32*)g,
      (__attribute__((address_space(3))) uint32*)l, 16, 0, 0);
}

// ---------------- weight packing (f32 -> packed f16) ----------------
__global__ __launch_bounds__(256) void pack_w(
    const float* __restrict__ w_ih_f, const float* __restrict__ w_ih_b,
    const float* __restrict__ mu_w, const float* __restrict__ lv_w,
    const float* __restrict__ sw_w1,
    const float* __restrict__ w_hh_f, const float* __restrict__ w_hh_b,
    const float* __restrict__ b_ih_f, const float* __restrict__ b_ih_b,
    const float* __restrict__ b_hh_f, const float* __restrict__ b_hh_b,
    const float* __restrict__ mu_b, const float* __restrict__ lv_b,
    const float* __restrict__ sw_b1,
    uint32* __restrict__ wihf, uint32* __restrict__ wihb,
    uint32* __restrict__ wchf, uint32* __restrict__ wchb, uint32* __restrict__ wce2,
    uint32* __restrict__ whh, uint32* __restrict__ w1z,
    float* __restrict__ biasc, float* __restrict__ biasf, float* __restrict__ biasb) {
  int id = blockIdx.x * 256 + threadIdx.x;
  if (id < 98304) { wihf[id] = pack2(w_ih_f[2*id], w_ih_f[2*id+1]); return; }
  id -= 98304;
  if (id < 98304) { wihb[id] = pack2(w_ih_b[2*id], w_ih_b[2*id+1]); return; }
  id -= 98304;
  if (id < 32768) {  // wchf (256x256): h_f columns of [mu_w|lv_w|w1_h]
    int n = id >> 7, c0 = (id & 127) * 2;
    const float* p = (n < 64)  ? mu_w + n * 512 + c0
                   : (n < 128) ? lv_w + (n - 64) * 512 + c0
                               : sw_w1 + (n - 128) * 832 + 256 + c0;
    wchf[id] = pack2(p[0], p[1]); return;
  }
  id -= 32768;
  if (id < 32768) {  // wchb (256x256): h_b columns
    int n = id >> 7, c0 = (id & 127) * 2;
    const float* p = (n < 64)  ? mu_w + n * 512 + 256 + c0
                   : (n < 128) ? lv_w + (n - 64) * 512 + 256 + c0
                               : sw_w1 + (n - 128) * 832 + 512 + c0;
    wchb[id] = pack2(p[0], p[1]); return;
  }
  id -= 32768;
  if (id < 16384) {  // wce2 (128x256): w1_e rows only
    int n = id >> 7, c0 = (id & 127) * 2;
    wce2[id] = pack2(sw_w1[n * 832 + c0], sw_w1[n * 832 + c0 + 1]); return;
  }
  id -= 16384;
  if (id < 196608) {  // whh2: [d][192][512] per-thread layout
    int dd = id / 98304, q = id % 98304;
    int j = q >> 9, t2 = q & 511;
    int rr = t2 >> 2, pp = t2 & 3;
    int gi = j >> 5, ck = j & 31;
    int g = gi >> 1, i = gi & 1;
    int row = 256 * g + 2 * rr + i;
    int k0 = pp * 64 + 2 * ck;
    const float* w = dd ? w_hh_b : w_hh_f;
    whh[id] = pack2(w[row * 256 + k0], w[row * 256 + k0 + 1]);
    return;
  }
  id -= 196608;
  if (id < 4096) {  // w1z2: [64][64] thread-k layout, rows (k, k+64)
    int j = id >> 6, kk = id & 63;
    int row = (j < 32) ? kk : kk + 64;
    int jj = j & 31;
    w1z[id] = pack2(sw_w1[row * 832 + 768 + 2 * jj], sw_w1[row * 832 + 768 + 2 * jj + 1]);
    return;
  }
  id -= 4096;
  if (id < 256) {
    biasc[id] = (id < 64) ? mu_b[id] : (id < 128) ? lv_b[id - 64] : sw_b1[id - 128];
    return;
  }
  id -= 256;
  if (id < 768) { biasf[id] = b_ih_f[id] + (id < 512 ? b_hh_f[id] : 0.f); return; }
  id -= 768;
  if (id < 768) { biasb[id] = b_ih_b[id] + (id < 512 ? b_hh_b[id] : 0.f); return; }
}

// ---------------- GEMM: C(MxN) = A(MxK) * B(N,K)^T [+bias] [+=C] ----------------
template <int AF32, int ACC>
__global__ __launch_bounds__(256) void gemm_t(
    const void* __restrict__ Ap, int lda,
    const half_t* __restrict__ Bw,  // (N,K) f16 row-major
    const float* __restrict__ bias,
    half_t* __restrict__ C, int ldc, int K) {
  __shared__ __align__(16) half_t smem[16384];
  half_t* As = smem;         // [128][64]
  half_t* Bs = smem + 8192;  // [128][64]
  const int tid = threadIdx.x;
  const int lane = tid & 63, w = tid >> 6;
  const int n0 = blockIdx.x * 128, m0 = blockIdx.y * 128;
  const int r8 = lane >> 3, c8 = lane & 7;
  f4_t acc[4][4];
  f4_t zero = {0.f, 0.f, 0.f, 0.f};
#pragma unroll
  for (int i = 0; i < 4; ++i)
#pragma unroll
    for (int j = 0; j < 4; ++j) acc[i][j] = zero;
  const int wm = (w >> 1) * 64, wn = (w & 1) * 64;
  for (int ks = 0; ks < K; ks += 64) {
    if constexpr (AF32) {
      const float* Af = (const float*)Ap;
#pragma unroll
      for (int it = 0; it < 4; ++it) {
        int c = it * 256 + tid;
        int row = c >> 3, coff = (c & 7) * 8;
        const float* ap = Af + (size_t)(m0 + row) * lda + ks + coff;
        float4 v0 = *(const float4*)ap;
        float4 v1 = *(const float4*)(ap + 4);
        uint4 u;
        u.x = pack2(v0.x, v0.y); u.y = pack2(v0.z, v0.w);
        u.z = pack2(v1.x, v1.y); u.w = pack2(v1.z, v1.w);
        *(uint4*)&As[(size_t)c * 8] = u;
      }
    } else {
      const half_t* Af = (const half_t*)Ap;
#pragma unroll
      for (int c = 0; c < 4; ++c) {
        int row = w * 32 + c * 8 + r8;
        gload_lds16(Af + (size_t)(m0 + row) * lda + ks + c8 * 8, As + (w * 4 + c) * 512);
      }
    }
#pragma unroll
    for (int c = 0; c < 4; ++c) {
      int row = w * 32 + c * 8 + r8;
      gload_lds16(Bw + (size_t)(n0 + row) * K + ks + c8 * 8, Bs + (w * 4 + c) * 512);
    }
    __syncthreads();
#pragma unroll
    for (int kk = 0; kk < 2; ++kk) {
      h8_t af[4], bf[4];
      const int ko = kk * 32 + (lane >> 4) * 8;
#pragma unroll
      for (int i = 0; i < 4; ++i) af[i] = *(const h8_t*)&As[(wm + i * 16 + (lane & 15)) * 64 + ko];
#pragma unroll
      for (int j = 0; j < 4; ++j) bf[j] = *(const h8_t*)&Bs[(wn + j * 16 + (lane & 15)) * 64 + ko];
#pragma unroll
      for (int i = 0; i < 4; ++i)
#pragma unroll
        for (int j = 0; j < 4; ++j)
          acc[i][j] = __builtin_amdgcn_mfma_f32_16x16x32_f16(af[i], bf[j], acc[i][j], 0, 0, 0);
    }
    __syncthreads();
  }
  const int cl4 = lane & 15, rl4 = lane >> 4;
#pragma unroll
  for (int j = 0; j < 4; ++j) {
    float bj = bias ? bias[n0 + wn + j * 16 + cl4] : 0.f;
#pragma unroll
    for (int i = 0; i < 4; ++i)
#pragma unroll
      for (int q = 0; q < 4; ++q) {
        int rl = wm + i * 16 + rl4 * 4 + q;
        int cc = wn + j * 16 + cl4;
        smem[rl * 128 + cc] = (half_t)(acc[i][j][q] + bj);
      }
  }
  __syncthreads();
#pragma unroll
  for (int it = 0; it < 8; ++it) {
    int idx = it * 256 + tid;
    int row = idx >> 4, colc = idx & 15;
    uint4 v = *(const uint4*)&smem[row * 128 + colc * 8];
    half_t* cp = C + (size_t)(m0 + row) * ldc + n0 + colc * 8;
    if constexpr (ACC) {
      uint4 o = *(const uint4*)cp;
      h8_t vv = __builtin_bit_cast(h8_t, v) + __builtin_bit_cast(h8_t, o);
      v = __builtin_bit_cast(uint4, vv);
    }
    *(uint4*)cp = v;
  }
}

// ---------------- GRU recurrence: weights pinned in VGPRs ----------------
// 128 WGs = (b, dir); 512 threads = 128 r-groups (2 hidden units) x 4 K-slices.
// h broadcast via padded LDS slices (stride 36 dwords -> conflict-free b128).
__global__ __launch_bounds__(512, 2) void gru_rec(
    uint32* __restrict__ xp,          // [2][B][T][384] dwords (f16 pairs)
    const uint32* __restrict__ whh2,  // [2][192][512]
    const float* __restrict__ bhh_f, const float* __restrict__ bhh_b) {
  const int wg = blockIdx.x;
  const int d = wg >> 6, b = wg & 63;
  const int tid = threadIdx.x;
  const int r = tid >> 2, p = tid & 3;
  __shared__ uint32 hb[2][144];  // 4 slices x (32 data + 4 pad) dwords
  if (tid < 144) { hb[0][tid] = 0; hb[1][tid] = 0; }
  uint32 wv[192];
  {
    const uint32* wp = whh2 + (size_t)d * 98304 + tid;
#pragma unroll
    for (int j = 0; j < 192; ++j) wv[j] = wp[(size_t)j * 512];
#pragma unroll
    for (int j = 0; j < 192; ++j) asm volatile("" : "+v"(wv[j]));
  }
  const float* bhh = d ? bhh_b : bhh_f;
  const float bhn0 = bhh[512 + 2 * r], bhn1 = bhh[512 + 2 * r + 1];
  uint32* xpu = xp + ((size_t)d * B_ + b) * T_ * 384;
  float h0 = 0.f, h1 = 0.f;
  const int dt = d ? -1 : 1;
  int t = d ? (T_ - 1) : 0;
  uint32 xr_n = 0, xz_n = 0, xn_n = 0;
  if (p == 0) {
    const uint32* rowp = xpu + (size_t)t * 384;
    xr_n = rowp[r]; xz_n = rowp[128 + r]; xn_n = rowp[256 + r];
  }
  const int rdbase = p * 36;
  const int wslice = (r >> 5) * 36 + (r & 31);
  __syncthreads();
  for (int step = 0; step < T_; ++step) {
    const int cur = step & 1;
    const uint32 xr = xr_n, xz = xz_n, xn = xn_n;
    const int tn = (step < T_ - 1) ? (t + dt) : t;
    if (p == 0) {
      const uint32* rowp = xpu + (size_t)tn * 384;
      xr_n = rowp[r]; xz_n = rowp[128 + r]; xn_n = rowp[256 + r];
    }
    float a00 = 0, a10 = 0, a01 = 0, a11 = 0, a02 = 0, a12 = 0;
    const uint32* hc = &hb[cur][rdbase];
#pragma unroll
    for (int c = 0; c < 4; ++c) {
      uint4 u0 = *(const uint4*)(hc + c * 8);
      uint4 u1 = *(const uint4*)(hc + c * 8 + 4);
      uint32 hv[8] = {u0.x, u0.y, u0.z, u0.w, u1.x, u1.y, u1.z, u1.w};
#pragma unroll
      for (int e = 0; e < 8; ++e) {
        const int j = c * 8 + e;
        half2_t hh = bch2(hv[e]);
        a00 = fdot2f(bch2(wv[j]),       hh, a00);
        a10 = fdot2f(bch2(wv[32 + j]),  hh, a10);
        a01 = fdot2f(bch2(wv[64 + j]),  hh, a01);
        a11 = fdot2f(bch2(wv[96 + j]),  hh, a11);
        a02 = fdot2f(bch2(wv[128 + j]), hh, a02);
        a12 = fdot2f(bch2(wv[160 + j]), hh, a12);
      }
    }
    a00 += __shfl_xor(a00, 1); a00 += __shfl_xor(a00, 2);
    a10 += __shfl_xor(a10, 1); a10 += __shfl_xor(a10, 2);
    a01 += __shfl_xor(a01, 1); a01 += __shfl_xor(a01, 2);
    a11 += __shfl_xor(a11, 1); a11 += __shfl_xor(a11, 2);
    a02 += __shfl_xor(a02, 1); a02 += __shfl_xor(a02, 2);
    a12 += __shfl_xor(a12, 1); a12 += __shfl_xor(a12, 2);
    if (p == 0) {
      half2_t xrv = bch2(xr), xzv = bch2(xz), xnv = bch2(xn);
      float r0 = sigmf((float)xrv.x + a00);
      float z0 = sigmf((float)xzv.x + a01);
      float n0 = tanhf_((float)xnv.x + r0 * (a02 + bhn0));
      h0 = (1.f - z0) * n0 + z0 * h0;
      float r1 = sigmf((float)xrv.y + a10);
      float z1 = sigmf((float)xzv.y + a11);
      float n1 = tanhf_((float)xnv.y + r1 * (a12 + bhn1));
      h1 = (1.f - z1) * n1 + z1 * h1;
      uint32 ph = pack2(h0, h1);
      hb[cur ^ 1][wslice] = ph;
      xpu[(size_t)t * 384 + r] = ph;  // in-place h store (xr slot dead)
    }
    __syncthreads();
    t = tn;
  }
}

// ---------------- z_tilde + KL partials ----------------
__global__ __launch_bounds__(256) void zkl(const half_t* __restrict__ hp,  // stride 768
                                           const float* __restrict__ eps,
                                           float* __restrict__ ztil,
                                           float* __restrict__ klp) {
  const int blk = blockIdx.x, tid = threadIdx.x;
  const size_t bt = (size_t)blk * 4 + (tid >> 6);
  const int j = tid & 63;
  float mu = (float)hp[bt * 768 + j];
  float lv = (float)hp[bt * 768 + 64 + j];
  float ev = eps[bt * 64 + j];
  ztil[bt * 64 + j] = mu + __expf(0.5f * lv) * ev;
  float term = 1.f + lv - mu * mu - __expf(lv);
#pragma unroll
  for (int s = 1; s < 64; s <<= 1) term += __shfl_xor(term, s);
  __shared__ float red[4];
  if ((tid & 63) == 0) red[tid >> 6] = term;
  __syncthreads();
  if (tid == 0) klp[blk] = red[0] + red[1] + red[2] + red[3];
}

__global__ __launch_bounds__(256) void klred(const float* __restrict__ klp,
                                             float* __restrict__ out) {
  const int tid = threadIdx.x;
  float s = 0.f;
  for (int i = tid; i < 16384; i += 256) s += klp[i];
#pragma unroll
  for (int st = 1; st < 64; st <<= 1) s += __shfl_xor(s, st);
  __shared__ float red[4];
  if ((tid & 63) == 0) red[tid >> 6] = s;
  __syncthreads();
  if (tid == 0) out[0] = (red[0] + red[1] + red[2] + red[3]) * (-0.5f / 65536.f);
}

// ---------------- sequential z-scan: ONE wave per batch element ----------------
__global__ __launch_bounds__(64) void z_scan(
    const half_t* __restrict__ hp,  // pre at col offset 128, stride 768
    const float* __restrict__ zt_arr,
    const uint32* __restrict__ w1z,  // [64][64] thread-k layout
    const float* __restrict__ sw_w2, const float* __restrict__ sw_b2,
    float* __restrict__ z_out, float* __restrict__ beta_out) {
  const int b = blockIdx.x;
  const int k = threadIdx.x;  // 0..63; owns hid rows k and k+64
  uint32 wz[64];
#pragma unroll
  for (int j = 0; j < 64; ++j) wz[j] = w1z[j * 64 + k];
#pragma unroll
  for (int j = 0; j < 64; ++j) asm volatile("" : "+v"(wz[j]));
  const float w2k0 = sw_w2[k], w2k1 = sw_w2[k + 64], b2 = sw_b2[0];
  __shared__ uint32 zb[2][32];
  if (k < 32) { zb[0][k] = 0; zb[1][k] = 0; }
  __syncthreads();
  float zf = 0.f;
  const size_t bt0 = (size_t)b * T_;
  float pre0n = (float)hp[bt0 * 768 + 128 + k];
  float pre1n = (float)hp[bt0 * 768 + 192 + k];
  float ztn = zt_arr[bt0 * 64 + k];
  for (int t = 0; t < T_; ++t) {
    const int cur = t & 1;
    const float pre0 = pre0n, pre1 = pre1n, zt = ztn;
    uint32 zr[32];
#pragma unroll
    for (int q = 0; q < 8; ++q) {
      uint4 u = *(const uint4*)&zb[cur][q * 4];
      zr[q * 4] = u.x; zr[q * 4 + 1] = u.y; zr[q * 4 + 2] = u.z; zr[q * 4 + 3] = u.w;
    }
    const int tn = (t < T_ - 1) ? t + 1 : t;
    pre0n = (float)hp[(bt0 + tn) * 768 + 128 + k];
    pre1n = (float)hp[(bt0 + tn) * 768 + 192 + k];
    ztn = zt_arr[(bt0 + tn) * 64 + k];
    float a0 = 0, a1 = 0, a2 = 0, a3 = 0;
#pragma unroll
    for (int j = 0; j < 32; j += 2) {
      a0 = fdot2f(bch2(wz[j]),          bch2(zr[j]),     a0);
      a1 = fdot2f(bch2(wz[j + 1]),      bch2(zr[j + 1]), a1);
      a2 = fdot2f(bch2(wz[32 + j]),     bch2(zr[j]),     a2);
      a3 = fdot2f(bch2(wz[32 + j + 1]), bch2(zr[j + 1]), a3);
    }
    float hid0 = fmaxf(pre0 + a0 + a1, 0.f);
    float hid1 = fmaxf(pre1 + a2 + a3, 0.f);
    float v = fmaf(hid0, w2k0, hid1 * w2k1);
#pragma unroll
    for (int s = 1; s < 64; s <<= 1) v += __shfl_xor(v, s);
    const float beta = sigmf(v + b2);
    zf = beta * zt + (1.f - beta) * zf;
    z_out[(bt0 + t) * 64 + k] = zf;
    if (k == 0) beta_out[bt0 + t] = beta;
    float zo = __shfl_xor(zf, 1);
    if ((k & 1) == 0) zb[cur ^ 1][k >> 1] = pack2(zf, zo);
    asm volatile("s_waitcnt lgkmcnt(0)" ::: "memory");  // single-wave LDS ordering
  }
}

extern "C" void kernel_launch(void* const* d_in, const int* in_sizes, int n_in,
                              void* d_out, int out_size, void* d_ws, size_t ws_size,
                              hipStream_t stream) {
  (void)in_sizes; (void)n_in; (void)out_size;
  const float* e_seq  = (const float*)d_in[0];
  const float* eps    = (const float*)d_in[1];
  const float* w_ih_f = (const float*)d_in[2];
  const float* w_hh_f = (const float*)d_in[3];
  const float* b_ih_f = (const float*)d_in[4];
  const float* b_hh_f = (const float*)d_in[5];
  const float* w_ih_b = (const float*)d_in[6];
  const float* w_hh_b = (const float*)d_in[7];
  const float* b_ih_b = (const float*)d_in[8];
  const float* b_hh_b = (const float*)d_in[9];
  const float* mu_w   = (const float*)d_in[10];
  const float* mu_b   = (const float*)d_in[11];
  const float* lv_w   = (const float*)d_in[12];
  const float* lv_b   = (const float*)d_in[13];
  const float* sw_w1  = (const float*)d_in[14];
  const float* sw_b1  = (const float*)d_in[15];
  const float* sw_w2  = (const float*)d_in[16];
  const float* sw_b2  = (const float*)d_in[17];

  // workspace: [0,100663296) xpf; [100663296,201326592) xpb; tail: packed weights
  const size_t NEED = 201326592 + 1924096;
  if (ws_size < NEED) return;
  char* ws = (char*)d_ws;
  half_t* xpf = (half_t*)ws;
  half_t* xpb = (half_t*)(ws + 100663296);
  half_t* hp  = xpf + 512;                      // heads cols [512,768), stride 768
  float*  ztil = (float*)(ws + 100663296);      // alias xpb (dead after head passes)
  float*  klp  = (float*)(ws + 100663296 + 16777216);
  char* wr = ws + 201326592;
  uint32* wihf  = (uint32*)(wr);                //  393216 B
  uint32* wihb  = (uint32*)(wr + 393216);       //  393216 B
  uint32* wchf  = (uint32*)(wr + 786432);       //  131072 B
  uint32* wchb  = (uint32*)(wr + 917504);       //  131072 B
  uint32* wce2  = (uint32*)(wr + 1048576);      //   65536 B
  uint32* whh2  = (uint32*)(wr + 1114112);      //  786432 B
  uint32* w1z2  = (uint32*)(wr + 1900544);      //   16384 B
  float*  biasc = (float*)(wr + 1916928);       //    1024 B
  float*  biasf = (float*)(wr + 1917952);       //    3072 B
  float*  biasb = (float*)(wr + 1921024);       //    3072 B

  pack_w<<<1879, 256, 0, stream>>>(w_ih_f, w_ih_b, mu_w, lv_w, sw_w1, w_hh_f, w_hh_b,
                                   b_ih_f, b_ih_b, b_hh_f, b_hh_b, mu_b, lv_b, sw_b1,
                                   wihf, wihb, wchf, wchb, wce2, whh2, w1z2,
                                   biasc, biasf, biasb);
  gemm_t<1, 0><<<dim3(6, 512), 256, 0, stream>>>(e_seq, 256, (const half_t*)wihf, biasf, xpf, 768, 256);
  gemm_t<1, 0><<<dim3(6, 512), 256, 0, stream>>>(e_seq, 256, (const half_t*)wihb, biasb, xpb, 768, 256);
  gru_rec<<<128, 512, 0, stream>>>((uint32*)ws, whh2, b_hh_f, b_hh_b);
  gemm_t<0, 0><<<dim3(2, 512), 256, 0, stream>>>(xpf, 768, (const half_t*)wchf, biasc, hp, 768, 256);
  gemm_t<0, 1><<<dim3(2, 512), 256, 0, stream>>>(xpb, 768, (const half_t*)wchb, nullptr, hp, 768, 256);
  gemm_t<1, 1><<<dim3(1, 512), 256, 0, stream>>>(e_seq, 256, (const half_t*)wce2, nullptr, hp + 128, 768, 256);
  zkl<<<16384, 256, 0, stream>>>(hp, eps, ztil, klp);
  klred<<<1, 256, 0, stream>>>(klp, (float*)d_out + 4194304);
  z_scan<<<64, 64, 0, stream>>>(hp, ztil, w1z2, sw_w2, sw_b2, (float*)d_out, (float*)d_out + 4194305);
}

// Round 4
// 2104.688 us; speedup vs baseline: 1.0205x; 1.0003x over previous
//
#include <hip/hip_runtime.h>
#include <cstdint>

typedef _Float16 half_t;
typedef _Float16 half2_t __attribute__((ext_vector_type(2)));
typedef _Float16 h8_t __attribute__((ext_vector_type(8)));
typedef float f4_t __attribute__((ext_vector_type(4)));
typedef unsigned int uint32;
typedef uint32 uv16 __attribute__((ext_vector_type(16)));

static constexpr int B_ = 64, T_ = 1024;

#define DEV __device__ __forceinline__

DEV float fdot2f(half2_t a, half2_t b, float c) {
#if __has_builtin(__builtin_amdgcn_fdot2)
  return __builtin_amdgcn_fdot2(a, b, c, false);
#else
  return fmaf((float)a.x, (float)b.x, fmaf((float)a.y, (float)b.y, c));
#endif
}

DEV float fast_rcp(float x) { return __builtin_amdgcn_rcpf(x); }
DEV float sigmf(float x) { return fast_rcp(1.f + __expf(-x)); }
DEV float tanhf_(float x) { return 1.f - 2.f * fast_rcp(1.f + __expf(2.f * x)); }
DEV uint32 pack2(float a, float b) {
  half2_t h; h.x = (half_t)a; h.y = (half_t)b;
  return __builtin_bit_cast(uint32, h);
}
DEV half2_t bch2(uint32 u) { return __builtin_bit_cast(half2_t, u); }

DEV void gload_lds16(const void* g, void* l) {
  __builtin_amdgcn_global_load_lds(
      (const __attribute__((address_space(1))) uint32*)g,
      (__attribute__((address_space(3))) uint32*)l, 16, 0, 0);
}

// select element j (compile-time) from the (va,vb) 32-dword pair
#define WSEL(va, vb, j) bch2(((j) < 16) ? (va)[(j) & 15] : (vb)[((j) - 16) & 15])

// ---------------- weight packing (f32 -> packed f16) ----------------
__global__ __launch_bounds__(256) void pack_w(
    const float* __restrict__ w_ih_f, const float* __restrict__ w_ih_b,
    const float* __restrict__ mu_w, const float* __restrict__ lv_w,
    const float* __restrict__ sw_w1,
    const float* __restrict__ w_hh_f, const float* __restrict__ w_hh_b,
    const float* __restrict__ b_ih_f, const float* __restrict__ b_ih_b,
    const float* __restrict__ b_hh_f, const float* __restrict__ b_hh_b,
    const float* __restrict__ mu_b, const float* __restrict__ lv_b,
    const float* __restrict__ sw_b1,
    uint32* __restrict__ wihf, uint32* __restrict__ wihb,
    uint32* __restrict__ wchf, uint32* __restrict__ wchb, uint32* __restrict__ wce2,
    uint32* __restrict__ whh, uint32* __restrict__ w1z,
    float* __restrict__ biasc, float* __restrict__ biasf, float* __restrict__ biasb) {
  int id = blockIdx.x * 256 + threadIdx.x;
  if (id < 98304) { wihf[id] = pack2(w_ih_f[2*id], w_ih_f[2*id+1]); return; }
  id -= 98304;
  if (id < 98304) { wihb[id] = pack2(w_ih_b[2*id], w_ih_b[2*id+1]); return; }
  id -= 98304;
  if (id < 32768) {  // wchf (256x256): h_f columns of [mu_w|lv_w|w1_h]
    int n = id >> 7, c0 = (id & 127) * 2;
    const float* p = (n < 64)  ? mu_w + n * 512 + c0
                   : (n < 128) ? lv_w + (n - 64) * 512 + c0
                               : sw_w1 + (n - 128) * 832 + 256 + c0;
    wchf[id] = pack2(p[0], p[1]); return;
  }
  id -= 32768;
  if (id < 32768) {  // wchb (256x256): h_b columns
    int n = id >> 7, c0 = (id & 127) * 2;
    const float* p = (n < 64)  ? mu_w + n * 512 + 256 + c0
                   : (n < 128) ? lv_w + (n - 64) * 512 + 256 + c0
                               : sw_w1 + (n - 128) * 832 + 512 + c0;
    wchb[id] = pack2(p[0], p[1]); return;
  }
  id -= 32768;
  if (id < 16384) {  // wce2 (128x256): w1_e rows only
    int n = id >> 7, c0 = (id & 127) * 2;
    wce2[id] = pack2(sw_w1[n * 832 + c0], sw_w1[n * 832 + c0 + 1]); return;
  }
  id -= 16384;
  if (id < 196608) {  // whh2: [d][192][512] per-thread layout
    int dd = id / 98304, q = id % 98304;
    int j = q >> 9, t2 = q & 511;
    int rr = t2 >> 2, pp = t2 & 3;
    int gi = j >> 5, ck = j & 31;
    int g = gi >> 1, i = gi & 1;
    int row = 256 * g + 2 * rr + i;
    int k0 = pp * 64 + 2 * ck;
    const float* w = dd ? w_hh_b : w_hh_f;
    whh[id] = pack2(w[row * 256 + k0], w[row * 256 + k0 + 1]);
    return;
  }
  id -= 196608;
  if (id < 4096) {  // w1z2: [64][64] thread-k layout, rows (k, k+64)
    int j = id >> 6, kk = id & 63;
    int row = (j < 32) ? kk : kk + 64;
    int jj = j & 31;
    w1z[id] = pack2(sw_w1[row * 832 + 768 + 2 * jj], sw_w1[row * 832 + 768 + 2 * jj + 1]);
    return;
  }
  id -= 4096;
  if (id < 256) {
    biasc[id] = (id < 64) ? mu_b[id] : (id < 128) ? lv_b[id - 64] : sw_b1[id - 128];
    return;
  }
  id -= 256;
  if (id < 768) { biasf[id] = b_ih_f[id] + (id < 512 ? b_hh_f[id] : 0.f); return; }
  id -= 768;
  if (id < 768) { biasb[id] = b_ih_b[id] + (id < 512 ? b_hh_b[id] : 0.f); return; }
}

// ---------------- GEMM: C(MxN) = A(MxK) * B(N,K)^T [+bias] [+=C] ----------------
template <int AF32, int ACC>
__global__ __launch_bounds__(256) void gemm_t(
    const void* __restrict__ Ap, int lda,
    const half_t* __restrict__ Bw,  // (N,K) f16 row-major
    const float* __restrict__ bias,
    half_t* __restrict__ C, int ldc, int K) {
  __shared__ __align__(16) half_t smem[16384];
  half_t* As = smem;         // [128][64]
  half_t* Bs = smem + 8192;  // [128][64]
  const int tid = threadIdx.x;
  const int lane = tid & 63, w = tid >> 6;
  const int n0 = blockIdx.x * 128, m0 = blockIdx.y * 128;
  const int r8 = lane >> 3, c8 = lane & 7;
  f4_t acc[4][4];
  f4_t zero = {0.f, 0.f, 0.f, 0.f};
#pragma unroll
  for (int i = 0; i < 4; ++i)
#pragma unroll
    for (int j = 0; j < 4; ++j) acc[i][j] = zero;
  const int wm = (w >> 1) * 64, wn = (w & 1) * 64;
  for (int ks = 0; ks < K; ks += 64) {
    if constexpr (AF32) {
      const float* Af = (const float*)Ap;
#pragma unroll
      for (int it = 0; it < 4; ++it) {
        int c = it * 256 + tid;
        int row = c >> 3, coff = (c & 7) * 8;
        const float* ap = Af + (size_t)(m0 + row) * lda + ks + coff;
        float4 v0 = *(const float4*)ap;
        float4 v1 = *(const float4*)(ap + 4);
        uint4 u;
        u.x = pack2(v0.x, v0.y); u.y = pack2(v0.z, v0.w);
        u.z = pack2(v1.x, v1.y); u.w = pack2(v1.z, v1.w);
        *(uint4*)&As[(size_t)c * 8] = u;
      }
    } else {
      const half_t* Af = (const half_t*)Ap;
#pragma unroll
      for (int c = 0; c < 4; ++c) {
        int row = w * 32 + c * 8 + r8;
        gload_lds16(Af + (size_t)(m0 + row) * lda + ks + c8 * 8, As + (w * 4 + c) * 512);
      }
    }
#pragma unroll
    for (int c = 0; c < 4; ++c) {
      int row = w * 32 + c * 8 + r8;
      gload_lds16(Bw + (size_t)(n0 + row) * K + ks + c8 * 8, Bs + (w * 4 + c) * 512);
    }
    __syncthreads();
#pragma unroll
    for (int kk = 0; kk < 2; ++kk) {
      h8_t af[4], bf[4];
      const int ko = kk * 32 + (lane >> 4) * 8;
#pragma unroll
      for (int i = 0; i < 4; ++i) af[i] = *(const h8_t*)&As[(wm + i * 16 + (lane & 15)) * 64 + ko];
#pragma unroll
      for (int j = 0; j < 4; ++j) bf[j] = *(const h8_t*)&Bs[(wn + j * 16 + (lane & 15)) * 64 + ko];
#pragma unroll
      for (int i = 0; i < 4; ++i)
#pragma unroll
        for (int j = 0; j < 4; ++j)
          acc[i][j] = __builtin_amdgcn_mfma_f32_16x16x32_f16(af[i], bf[j], acc[i][j], 0, 0, 0);
    }
    __syncthreads();
  }
  const int cl4 = lane & 15, rl4 = lane >> 4;
#pragma unroll
  for (int j = 0; j < 4; ++j) {
    float bj = bias ? bias[n0 + wn + j * 16 + cl4] : 0.f;
#pragma unroll
    for (int i = 0; i < 4; ++i)
#pragma unroll
      for (int q = 0; q < 4; ++q) {
        int rl = wm + i * 16 + rl4 * 4 + q;
        int cc = wn + j * 16 + cl4;
        smem[rl * 128 + cc] = (half_t)(acc[i][j][q] + bj);
      }
  }
  __syncthreads();
#pragma unroll
  for (int it = 0; it < 8; ++it) {
    int idx = it * 256 + tid;
    int row = idx >> 4, colc = idx & 15;
    uint4 v = *(const uint4*)&smem[row * 128 + colc * 8];
    half_t* cp = C + (size_t)(m0 + row) * ldc + n0 + colc * 8;
    if constexpr (ACC) {
      uint4 o = *(const uint4*)cp;
      h8_t vv = __builtin_bit_cast(h8_t, v) + __builtin_bit_cast(h8_t, o);
      v = __builtin_bit_cast(uint4, vv);
    }
    *(uint4*)cp = v;
  }
}

// ---------------- GRU recurrence: weights in named SSA vector registers ----------------
// 128 WGs = (b, dir); 512 threads = 128 r-groups (2 hidden units) x 4 K-slices.
__global__ __launch_bounds__(512, 2) void gru_rec(
    uint32* __restrict__ xp,          // [2][B][T][384] dwords (f16 pairs)
    const uint32* __restrict__ whh2,  // [2][192][512]
    const float* __restrict__ bhh_f, const float* __restrict__ bhh_b) {
  const int wg = blockIdx.x;
  const int d = wg >> 6, b = wg & 63;
  const int tid = threadIdx.x;
  const int r = tid >> 2, p = tid & 3;
  __shared__ uint32 hb[2][144];  // 4 slices x (32 data + 4 pad) dwords
  if (tid < 144) { hb[0][tid] = 0; hb[1][tid] = 0; }
  // 192 weights in 12 named 16-dword vectors (no alloca -> no scratch)
  uv16 w0a, w0b, w1a, w1b, w2a, w2b, w3a, w3b, w4a, w4b, w5a, w5b;
  {
    const uint32* wp = whh2 + (size_t)d * 98304 + tid;
#define LD16(vec, base)                                   \
  _Pragma("unroll") for (int e = 0; e < 16; ++e) vec[e] = \
      wp[(size_t)((base) + e) * 512];
    LD16(w0a, 0);   LD16(w0b, 16);  LD16(w1a, 32);  LD16(w1b, 48);
    LD16(w2a, 64);  LD16(w2b, 80);  LD16(w3a, 96);  LD16(w3b, 112);
    LD16(w4a, 128); LD16(w4b, 144); LD16(w5a, 160); LD16(w5b, 176);
#undef LD16
    asm volatile("" : "+v"(w0a), "+v"(w0b), "+v"(w1a), "+v"(w1b), "+v"(w2a), "+v"(w2b));
    asm volatile("" : "+v"(w3a), "+v"(w3b), "+v"(w4a), "+v"(w4b), "+v"(w5a), "+v"(w5b));
  }
  const float* bhh = d ? bhh_b : bhh_f;
  const float bhn0 = bhh[512 + 2 * r], bhn1 = bhh[512 + 2 * r + 1];
  uint32* xpu = xp + ((size_t)d * B_ + b) * T_ * 384;
  float h0 = 0.f, h1 = 0.f;
  const int dt = d ? -1 : 1;
  int t = d ? (T_ - 1) : 0;
  uint32 xr_n = 0, xz_n = 0, xn_n = 0;
  if (p == 0) {
    const uint32* rowp = xpu + (size_t)t * 384;
    xr_n = rowp[r]; xz_n = rowp[128 + r]; xn_n = rowp[256 + r];
  }
  const int rdbase = p * 36;
  const int wslice = (r >> 5) * 36 + (r & 31);
  __syncthreads();
  for (int step = 0; step < T_; ++step) {
    const int cur = step & 1;
    const uint32 xr = xr_n, xz = xz_n, xn = xn_n;
    const int tn = (step < T_ - 1) ? (t + dt) : t;
    if (p == 0) {
      const uint32* rowp = xpu + (size_t)tn * 384;
      xr_n = rowp[r]; xz_n = rowp[128 + r]; xn_n = rowp[256 + r];
    }
    float a00 = 0, a10 = 0, a01 = 0, a11 = 0, a02 = 0, a12 = 0;
    const uint32* hc = &hb[cur][rdbase];
#pragma unroll
    for (int c = 0; c < 4; ++c) {
      uint4 u0 = *(const uint4*)(hc + c * 8);
      uint4 u1 = *(const uint4*)(hc + c * 8 + 4);
      uint32 hv[8] = {u0.x, u0.y, u0.z, u0.w, u1.x, u1.y, u1.z, u1.w};
#pragma unroll
      for (int e = 0; e < 8; ++e) {
        const int j = c * 8 + e;
        half2_t hh = bch2(hv[e]);
        a00 = fdot2f(WSEL(w0a, w0b, j), hh, a00);
        a10 = fdot2f(WSEL(w1a, w1b, j), hh, a10);
        a01 = fdot2f(WSEL(w2a, w2b, j), hh, a01);
        a11 = fdot2f(WSEL(w3a, w3b, j), hh, a11);
        a02 = fdot2f(WSEL(w4a, w4b, j), hh, a02);
        a12 = fdot2f(WSEL(w5a, w5b, j), hh, a12);
      }
    }
    a00 += __shfl_xor(a00, 1); a00 += __shfl_xor(a00, 2);
    a10 += __shfl_xor(a10, 1); a10 += __shfl_xor(a10, 2);
    a01 += __shfl_xor(a01, 1); a01 += __shfl_xor(a01, 2);
    a11 += __shfl_xor(a11, 1); a11 += __shfl_xor(a11, 2);
    a02 += __shfl_xor(a02, 1); a02 += __shfl_xor(a02, 2);
    a12 += __shfl_xor(a12, 1); a12 += __shfl_xor(a12, 2);
    if (p == 0) {
      half2_t xrv = bch2(xr), xzv = bch2(xz), xnv = bch2(xn);
      float r0 = sigmf((float)xrv.x + a00);
      float z0 = sigmf((float)xzv.x + a01);
      float n0 = tanhf_((float)xnv.x + r0 * (a02 + bhn0));
      h0 = (1.f - z0) * n0 + z0 * h0;
      float r1 = sigmf((float)xrv.y + a10);
      float z1 = sigmf((float)xzv.y + a11);
      float n1 = tanhf_((float)xnv.y + r1 * (a12 + bhn1));
      h1 = (1.f - z1) * n1 + z1 * h1;
      uint32 ph = pack2(h0, h1);
      hb[cur ^ 1][wslice] = ph;
      xpu[(size_t)t * 384 + r] = ph;  // in-place h store (xr slot dead)
    }
    __syncthreads();
    t = tn;
  }
}

// ---------------- z_tilde + KL partials ----------------
__global__ __launch_bounds__(256) void zkl(const half_t* __restrict__ hp,  // stride 768
                                           const float* __restrict__ eps,
                                           float* __restrict__ ztil,
                                           float* __restrict__ klp) {
  const int blk = blockIdx.x, tid = threadIdx.x;
  const size_t bt = (size_t)blk * 4 + (tid >> 6);
  const int j = tid & 63;
  float mu = (float)hp[bt * 768 + j];
  float lv = (float)hp[bt * 768 + 64 + j];
  float ev = eps[bt * 64 + j];
  ztil[bt * 64 + j] = mu + __expf(0.5f * lv) * ev;
  float term = 1.f + lv - mu * mu - __expf(lv);
#pragma unroll
  for (int s = 1; s < 64; s <<= 1) term += __shfl_xor(term, s);
  __shared__ float red[4];
  if ((tid & 63) == 0) red[tid >> 6] = term;
  __syncthreads();
  if (tid == 0) klp[blk] = red[0] + red[1] + red[2] + red[3];
}

__global__ __launch_bounds__(256) void klred(const float* __restrict__ klp,
                                             float* __restrict__ out) {
  const int tid = threadIdx.x;
  float s = 0.f;
  for (int i = tid; i < 16384; i += 256) s += klp[i];
#pragma unroll
  for (int st = 1; st < 64; st <<= 1) s += __shfl_xor(s, st);
  __shared__ float red[4];
  if ((tid & 63) == 0) red[tid >> 6] = s;
  __syncthreads();
  if (tid == 0) out[0] = (red[0] + red[1] + red[2] + red[3]) * (-0.5f / 65536.f);
}

// ---------------- sequential z-scan: ONE wave per batch element ----------------
__global__ __launch_bounds__(64) void z_scan(
    const half_t* __restrict__ hp,  // pre at col offset 128, stride 768
    const float* __restrict__ zt_arr,
    const uint32* __restrict__ w1z,  // [64][64] thread-k layout
    const float* __restrict__ sw_w2, const float* __restrict__ sw_b2,
    float* __restrict__ z_out, float* __restrict__ beta_out) {
  const int b = blockIdx.x;
  const int k = threadIdx.x;  // 0..63; owns hid rows k and k+64
  uv16 z0a, z0b, z1a, z1b;    // 64 weights in named vectors
  {
#define LDZ(vec, base)                                    \
  _Pragma("unroll") for (int e = 0; e < 16; ++e) vec[e] = \
      w1z[((base) + e) * 64 + k];
    LDZ(z0a, 0); LDZ(z0b, 16); LDZ(z1a, 32); LDZ(z1b, 48);
#undef LDZ
    asm volatile("" : "+v"(z0a), "+v"(z0b), "+v"(z1a), "+v"(z1b));
  }
  const float w2k0 = sw_w2[k], w2k1 = sw_w2[k + 64], b2 = sw_b2[0];
  __shared__ uint32 zbuf[2][32];
  if (k < 32) { zbuf[0][k] = 0; zbuf[1][k] = 0; }
  __syncthreads();
  float zf = 0.f;
  const size_t bt0 = (size_t)b * T_;
  float pre0n = (float)hp[bt0 * 768 + 128 + k];
  float pre1n = (float)hp[bt0 * 768 + 192 + k];
  float ztn = zt_arr[bt0 * 64 + k];
  for (int t = 0; t < T_; ++t) {
    const int cur = t & 1;
    const float pre0 = pre0n, pre1 = pre1n, zt = ztn;
    const int tn = (t < T_ - 1) ? t + 1 : t;
    pre0n = (float)hp[(bt0 + tn) * 768 + 128 + k];
    pre1n = (float)hp[(bt0 + tn) * 768 + 192 + k];
    ztn = zt_arr[(bt0 + tn) * 64 + k];
    float a0 = 0, a1 = 0, a2 = 0, a3 = 0;
#pragma unroll
    for (int q = 0; q < 8; ++q) {
      uint4 u = *(const uint4*)&zbuf[cur][q * 4];
      const int m = q * 4;
      a0 = fdot2f(WSEL(z0a, z0b, m),     bch2(u.x), a0);
      a1 = fdot2f(WSEL(z0a, z0b, m + 1), bch2(u.y), a1);
      a0 = fdot2f(WSEL(z0a, z0b, m + 2), bch2(u.z), a0);
      a1 = fdot2f(WSEL(z0a, z0b, m + 3), bch2(u.w), a1);
      a2 = fdot2f(WSEL(z1a, z1b, m),     bch2(u.x), a2);
      a3 = fdot2f(WSEL(z1a, z1b, m + 1), bch2(u.y), a3);
      a2 = fdot2f(WSEL(z1a, z1b, m + 2), bch2(u.z), a2);
      a3 = fdot2f(WSEL(z1a, z1b, m + 3), bch2(u.w), a3);
    }
    float hid0 = fmaxf(pre0 + a0 + a1, 0.f);
    float hid1 = fmaxf(pre1 + a2 + a3, 0.f);
    float v = fmaf(hid0, w2k0, hid1 * w2k1);
#pragma unroll
    for (int s = 1; s < 64; s <<= 1) v += __shfl_xor(v, s);
    const float beta = sigmf(v + b2);
    zf = beta * zt + (1.f - beta) * zf;
    z_out[(bt0 + t) * 64 + k] = zf;
    if (k == 0) beta_out[bt0 + t] = beta;
    float zo = __shfl_xor(zf, 1);
    if ((k & 1) == 0) zbuf[cur ^ 1][k >> 1] = pack2(zf, zo);
    asm volatile("s_waitcnt lgkmcnt(0)" ::: "memory");  // single-wave LDS ordering
  }
}

extern "C" void kernel_launch(void* const* d_in, const int* in_sizes, int n_in,
                              void* d_out, int out_size, void* d_ws, size_t ws_size,
                              hipStream_t stream) {
  (void)in_sizes; (void)n_in; (void)out_size;
  const float* e_seq  = (const float*)d_in[0];
  const float* eps    = (const float*)d_in[1];
  const float* w_ih_f = (const float*)d_in[2];
  const float* w_hh_f = (const float*)d_in[3];
  const float* b_ih_f = (const float*)d_in[4];
  const float* b_hh_f = (const float*)d_in[5];
  const float* w_ih_b = (const float*)d_in[6];
  const float* w_hh_b = (const float*)d_in[7];
  const float* b_ih_b = (const float*)d_in[8];
  const float* b_hh_b = (const float*)d_in[9];
  const float* mu_w   = (const float*)d_in[10];
  const float* mu_b   = (const float*)d_in[11];
  const float* lv_w   = (const float*)d_in[12];
  const float* lv_b   = (const float*)d_in[13];
  const float* sw_w1  = (const float*)d_in[14];
  const float* sw_b1  = (const float*)d_in[15];
  const float* sw_w2  = (const float*)d_in[16];
  const float* sw_b2  = (const float*)d_in[17];

  // workspace: [0,100663296) xpf; [100663296,201326592) xpb; tail: packed weights
  const size_t NEED = 201326592 + 1924096;
  if (ws_size < NEED) return;
  char* ws = (char*)d_ws;
  half_t* xpf = (half_t*)ws;
  half_t* xpb = (half_t*)(ws + 100663296);
  half_t* hp  = xpf + 512;                      // heads cols [512,768), stride 768
  float*  ztil = (float*)(ws + 100663296);      // alias xpb (dead after head passes)
  float*  klp  = (float*)(ws + 100663296 + 16777216);
  char* wr = ws + 201326592;
  uint32* wihf  = (uint32*)(wr);                //  393216 B
  uint32* wihb  = (uint32*)(wr + 393216);       //  393216 B
  uint32* wchf  = (uint32*)(wr + 786432);       //  131072 B
  uint32* wchb  = (uint32*)(wr + 917504);       //  131072 B
  uint32* wce2  = (uint32*)(wr + 1048576);      //   65536 B
  uint32* whh2  = (uint32*)(wr + 1114112);      //  786432 B
  uint32* w1z2  = (uint32*)(wr + 1900544);      //   16384 B
  float*  biasc = (float*)(wr + 1916928);       //    1024 B
  float*  biasf = (float*)(wr + 1917952);       //    3072 B
  float*  biasb = (float*)(wr + 1921024);       //    3072 B

  pack_w<<<1879, 256, 0, stream>>>(w_ih_f, w_ih_b, mu_w, lv_w, sw_w1, w_hh_f, w_hh_b,
                                   b_ih_f, b_ih_b, b_hh_f, b_hh_b, mu_b, lv_b, sw_b1,
                                   wihf, wihb, wchf, wchb, wce2, whh2, w1z2,
                                   biasc, biasf, biasb);
  gemm_t<1, 0><<<dim3(6, 512), 256, 0, stream>>>(e_seq, 256, (const half_t*)wihf, biasf, xpf, 768, 256);
  gemm_t<1, 0><<<dim3(6, 512), 256, 0, stream>>>(e_seq, 256, (const half_t*)wihb, biasb, xpb, 768, 256);
  gru_rec<<<128, 512, 0, stream>>>((uint32*)ws, whh2, b_hh_f, b_hh_b);
  gemm_t<0, 0><<<dim3(2, 512), 256, 0, stream>>>(xpf, 768, (const half_t*)wchf, biasc, hp, 768, 256);
  gemm_t<0, 1><<<dim3(2, 512), 256, 0, stream>>>(xpb, 768, (const half_t*)wchb, nullptr, hp, 768, 256);
  gemm_t<1, 1><<<dim3(1, 512), 256, 0, stream>>>(e_seq, 256, (const half_t*)wce2, nullptr, hp + 128, 768, 256);
  zkl<<<16384, 256, 0, stream>>>(hp, eps, ztil, klp);
  klred<<<1, 256, 0, stream>>>(klp, (float*)d_out + 4194304);
  z_scan<<<64, 64, 0, stream>>>(hp, ztil, w1z2, sw_w2, sw_b2, (float*)d_out, (float*)d_out + 4194305);
}

// Round 5
// 2102.504 us; speedup vs baseline: 1.0216x; 1.0010x over previous
//
#include <hip/hip_runtime.h>
#include <cstdint>

typedef _Float16 half_t;
typedef _Float16 half2_t __attribute__((ext_vector_type(2)));
typedef _Float16 h8_t __attribute__((ext_vector_type(8)));
typedef float f4_t __attribute__((ext_vector_type(4)));
typedef unsigned int uint32;
typedef uint32 uv16 __attribute__((ext_vector_type(16)));

static constexpr int B_ = 64, T_ = 1024;

#define DEV __device__ __forceinline__

DEV float fdot2f(half2_t a, half2_t b, float c) {
#if __has_builtin(__builtin_amdgcn_fdot2)
  return __builtin_amdgcn_fdot2(a, b, c, false);
#else
  return fmaf((float)a.x, (float)b.x, fmaf((float)a.y, (float)b.y, c));
#endif
}

DEV float fast_rcp(float x) { return __builtin_amdgcn_rcpf(x); }
DEV float sigmf(float x) { return fast_rcp(1.f + __expf(-x)); }
DEV float tanhf_(float x) { return 1.f - 2.f * fast_rcp(1.f + __expf(2.f * x)); }
DEV uint32 pack2(float a, float b) {
  half2_t h; h.x = (half_t)a; h.y = (half_t)b;
  return __builtin_bit_cast(uint32, h);
}
DEV half2_t bch2(uint32 u) { return __builtin_bit_cast(half2_t, u); }

DEV void gload_lds16(const void* g, void* l) {
  __builtin_amdgcn_global_load_lds(
      (const __attribute__((address_space(1))) uint32*)g,
      (__attribute__((address_space(3))) uint32*)l, 16, 0, 0);
}

// select element j (compile-time) from the (va,vb) 32-dword pair
#define WSEL(va, vb, j) bch2(((j) < 16) ? (va)[(j) & 15] : (vb)[((j) - 16) & 15])

// ---------------- weight packing (f32 -> packed f16) ----------------
__global__ __launch_bounds__(256) void pack_w(
    const float* __restrict__ w_ih_f, const float* __restrict__ w_ih_b,
    const float* __restrict__ mu_w, const float* __restrict__ lv_w,
    const float* __restrict__ sw_w1,
    const float* __restrict__ w_hh_f, const float* __restrict__ w_hh_b,
    const float* __restrict__ b_ih_f, const float* __restrict__ b_ih_b,
    const float* __restrict__ b_hh_f, const float* __restrict__ b_hh_b,
    const float* __restrict__ mu_b, const float* __restrict__ lv_b,
    const float* __restrict__ sw_b1,
    uint32* __restrict__ wihf, uint32* __restrict__ wihb,
    uint32* __restrict__ wchf, uint32* __restrict__ wchb, uint32* __restrict__ wce2,
    uint32* __restrict__ whh, uint32* __restrict__ w1z,
    float* __restrict__ biasc, float* __restrict__ biasf, float* __restrict__ biasb) {
  int id = blockIdx.x * 256 + threadIdx.x;
  if (id < 98304) { wihf[id] = pack2(w_ih_f[2*id], w_ih_f[2*id+1]); return; }
  id -= 98304;
  if (id < 98304) { wihb[id] = pack2(w_ih_b[2*id], w_ih_b[2*id+1]); return; }
  id -= 98304;
  if (id < 32768) {  // wchf (256x256): h_f columns of [mu_w|lv_w|w1_h]
    int n = id >> 7, c0 = (id & 127) * 2;
    const float* p = (n < 64)  ? mu_w + n * 512 + c0
                   : (n < 128) ? lv_w + (n - 64) * 512 + c0
                               : sw_w1 + (n - 128) * 832 + 256 + c0;
    wchf[id] = pack2(p[0], p[1]); return;
  }
  id -= 32768;
  if (id < 32768) {  // wchb (256x256): h_b columns
    int n = id >> 7, c0 = (id & 127) * 2;
    const float* p = (n < 64)  ? mu_w + n * 512 + 256 + c0
                   : (n < 128) ? lv_w + (n - 64) * 512 + 256 + c0
                               : sw_w1 + (n - 128) * 832 + 512 + c0;
    wchb[id] = pack2(p[0], p[1]); return;
  }
  id -= 32768;
  if (id < 16384) {  // wce2 (128x256): w1_e rows only
    int n = id >> 7, c0 = (id & 127) * 2;
    wce2[id] = pack2(sw_w1[n * 832 + c0], sw_w1[n * 832 + c0 + 1]); return;
  }
  id -= 16384;
  if (id < 196608) {  // whh2: [d][192][512] per-thread layout
    int dd = id / 98304, q = id % 98304;
    int j = q >> 9, t2 = q & 511;
    int rr = t2 >> 2, pp = t2 & 3;
    int gi = j >> 5, ck = j & 31;
    int g = gi >> 1, i = gi & 1;
    int row = 256 * g + 2 * rr + i;
    int k0 = pp * 64 + 2 * ck;
    const float* w = dd ? w_hh_b : w_hh_f;
    whh[id] = pack2(w[row * 256 + k0], w[row * 256 + k0 + 1]);
    return;
  }
  id -= 196608;
  if (id < 4096) {  // w1z2: [64][64] thread-k layout, rows (k, k+64)
    int j = id >> 6, kk = id & 63;
    int row = (j < 32) ? kk : kk + 64;
    int jj = j & 31;
    w1z[id] = pack2(sw_w1[row * 832 + 768 + 2 * jj], sw_w1[row * 832 + 768 + 2 * jj + 1]);
    return;
  }
  id -= 4096;
  if (id < 256) {
    biasc[id] = (id < 64) ? mu_b[id] : (id < 128) ? lv_b[id - 64] : sw_b1[id - 128];
    return;
  }
  id -= 256;
  if (id < 768) { biasf[id] = b_ih_f[id] + (id < 512 ? b_hh_f[id] : 0.f); return; }
  id -= 768;
  if (id < 768) { biasb[id] = b_ih_b[id] + (id < 512 ? b_hh_b[id] : 0.f); return; }
}

// ---------------- GEMM: C(MxN) = A(MxK) * B(N,K)^T [+bias] [+=C] ----------------
template <int AF32, int ACC>
__global__ __launch_bounds__(256) void gemm_t(
    const void* __restrict__ Ap, int lda,
    const half_t* __restrict__ Bw,  // (N,K) f16 row-major
    const float* __restrict__ bias,
    half_t* __restrict__ C, int ldc, int K) {
  __shared__ __align__(16) half_t smem[16384];
  half_t* As = smem;         // [128][64]
  half_t* Bs = smem + 8192;  // [128][64]
  const int tid = threadIdx.x;
  const int lane = tid & 63, w = tid >> 6;
  const int n0 = blockIdx.x * 128, m0 = blockIdx.y * 128;
  const int r8 = lane >> 3, c8 = lane & 7;
  f4_t acc[4][4];
  f4_t zero = {0.f, 0.f, 0.f, 0.f};
#pragma unroll
  for (int i = 0; i < 4; ++i)
#pragma unroll
    for (int j = 0; j < 4; ++j) acc[i][j] = zero;
  const int wm = (w >> 1) * 64, wn = (w & 1) * 64;
  for (int ks = 0; ks < K; ks += 64) {
    if constexpr (AF32) {
      const float* Af = (const float*)Ap;
#pragma unroll
      for (int it = 0; it < 4; ++it) {
        int c = it * 256 + tid;
        int row = c >> 3, coff = (c & 7) * 8;
        const float* ap = Af + (size_t)(m0 + row) * lda + ks + coff;
        float4 v0 = *(const float4*)ap;
        float4 v1 = *(const float4*)(ap + 4);
        uint4 u;
        u.x = pack2(v0.x, v0.y); u.y = pack2(v0.z, v0.w);
        u.z = pack2(v1.x, v1.y); u.w = pack2(v1.z, v1.w);
        *(uint4*)&As[(size_t)c * 8] = u;
      }
    } else {
      const half_t* Af = (const half_t*)Ap;
#pragma unroll
      for (int c = 0; c < 4; ++c) {
        int row = w * 32 + c * 8 + r8;
        gload_lds16(Af + (size_t)(m0 + row) * lda + ks + c8 * 8, As + (w * 4 + c) * 512);
      }
    }
#pragma unroll
    for (int c = 0; c < 4; ++c) {
      int row = w * 32 + c * 8 + r8;
      gload_lds16(Bw + (size_t)(n0 + row) * K + ks + c8 * 8, Bs + (w * 4 + c) * 512);
    }
    __syncthreads();
#pragma unroll
    for (int kk = 0; kk < 2; ++kk) {
      h8_t af[4], bf[4];
      const int ko = kk * 32 + (lane >> 4) * 8;
#pragma unroll
      for (int i = 0; i < 4; ++i) af[i] = *(const h8_t*)&As[(wm + i * 16 + (lane & 15)) * 64 + ko];
#pragma unroll
      for (int j = 0; j < 4; ++j) bf[j] = *(const h8_t*)&Bs[(wn + j * 16 + (lane & 15)) * 64 + ko];
#pragma unroll
      for (int i = 0; i < 4; ++i)
#pragma unroll
        for (int j = 0; j < 4; ++j)
          acc[i][j] = __builtin_amdgcn_mfma_f32_16x16x32_f16(af[i], bf[j], acc[i][j], 0, 0, 0);
    }
    __syncthreads();
  }
  const int cl4 = lane & 15, rl4 = lane >> 4;
#pragma unroll
  for (int j = 0; j < 4; ++j) {
    float bj = bias ? bias[n0 + wn + j * 16 + cl4] : 0.f;
#pragma unroll
    for (int i = 0; i < 4; ++i)
#pragma unroll
      for (int q = 0; q < 4; ++q) {
        int rl = wm + i * 16 + rl4 * 4 + q;
        int cc = wn + j * 16 + cl4;
        smem[rl * 128 + cc] = (half_t)(acc[i][j][q] + bj);
      }
  }
  __syncthreads();
#pragma unroll
  for (int it = 0; it < 8; ++it) {
    int idx = it * 256 + tid;
    int row = idx >> 4, colc = idx & 15;
    uint4 v = *(const uint4*)&smem[row * 128 + colc * 8];
    half_t* cp = C + (size_t)(m0 + row) * ldc + n0 + colc * 8;
    if constexpr (ACC) {
      uint4 o = *(const uint4*)cp;
      h8_t vv = __builtin_bit_cast(h8_t, v) + __builtin_bit_cast(h8_t, o);
      v = __builtin_bit_cast(uint4, vv);
    }
    *(uint4*)cp = v;
  }
}

// ---------------- GRU recurrence: weights in named SSA vector registers ----------------
// 128 WGs = (b, dir); 512 threads = 128 r-groups (2 hidden units) x 4 K-slices.
// amdgpu_waves_per_eu(2,2): force 256-VGPR budget so weights stay resident
// (launch_bounds' min-waves arg alone lets the allocator target 4 waves/EU
// and remat the weight loads from L2 every step -> 39 TB/s L2-bound, R2-R4).
__global__ __attribute__((amdgpu_flat_work_group_size(512, 512)))
__attribute__((amdgpu_waves_per_eu(2, 2))) void gru_rec(
    uint32* __restrict__ xp,          // [2][B][T][384] dwords (f16 pairs)
    const uint32* __restrict__ whh2,  // [2][192][512]
    const float* __restrict__ bhh_f, const float* __restrict__ bhh_b) {
  const int wg = blockIdx.x;
  const int d = wg >> 6, b = wg & 63;
  const int tid = threadIdx.x;
  const int r = tid >> 2, p = tid & 3;
  __shared__ uint32 hb[2][144];  // 4 slices x (32 data + 4 pad) dwords
  if (tid < 144) { hb[0][tid] = 0; hb[1][tid] = 0; }
  // 192 weights in 12 named 16-dword vectors (no alloca -> no scratch)
  uv16 w0a, w0b, w1a, w1b, w2a, w2b, w3a, w3b, w4a, w4b, w5a, w5b;
  {
    const uint32* wp = whh2 + (size_t)d * 98304 + tid;
#define LD16(vec, base)                                   \
  _Pragma("unroll") for (int e = 0; e < 16; ++e) vec[e] = \
      wp[(size_t)((base) + e) * 512];
    LD16(w0a, 0);   LD16(w0b, 16);  LD16(w1a, 32);  LD16(w1b, 48);
    LD16(w2a, 64);  LD16(w2b, 80);  LD16(w3a, 96);  LD16(w3b, 112);
    LD16(w4a, 128); LD16(w4b, 144); LD16(w5a, 160); LD16(w5b, 176);
#undef LD16
    asm volatile("" : "+v"(w0a), "+v"(w0b), "+v"(w1a), "+v"(w1b), "+v"(w2a), "+v"(w2b));
    asm volatile("" : "+v"(w3a), "+v"(w3b), "+v"(w4a), "+v"(w4b), "+v"(w5a), "+v"(w5b));
  }
  const float* bhh = d ? bhh_b : bhh_f;
  const float bhn0 = bhh[512 + 2 * r], bhn1 = bhh[512 + 2 * r + 1];
  uint32* xpu = xp + ((size_t)d * B_ + b) * T_ * 384;
  float h0 = 0.f, h1 = 0.f;
  const int dt = d ? -1 : 1;
  int t = d ? (T_ - 1) : 0;
  uint32 xr_n = 0, xz_n = 0, xn_n = 0;
  if (p == 0) {
    const uint32* rowp = xpu + (size_t)t * 384;
    xr_n = rowp[r]; xz_n = rowp[128 + r]; xn_n = rowp[256 + r];
  }
  const int rdbase = p * 36;
  const int wslice = (r >> 5) * 36 + (r & 31);
  __syncthreads();
  for (int step = 0; step < T_; ++step) {
    const int cur = step & 1;
    const uint32 xr = xr_n, xz = xz_n, xn = xn_n;
    const int tn = (step < T_ - 1) ? (t + dt) : t;
    if (p == 0) {
      const uint32* rowp = xpu + (size_t)tn * 384;
      xr_n = rowp[r]; xz_n = rowp[128 + r]; xn_n = rowp[256 + r];
    }
    float a00 = 0, a10 = 0, a01 = 0, a11 = 0, a02 = 0, a12 = 0;
    const uint32* hc = &hb[cur][rdbase];
#pragma unroll
    for (int c = 0; c < 4; ++c) {
      uint4 u0 = *(const uint4*)(hc + c * 8);
      uint4 u1 = *(const uint4*)(hc + c * 8 + 4);
      uint32 hv[8] = {u0.x, u0.y, u0.z, u0.w, u1.x, u1.y, u1.z, u1.w};
#pragma unroll
      for (int e = 0; e < 8; ++e) {
        const int j = c * 8 + e;
        half2_t hh = bch2(hv[e]);
        a00 = fdot2f(WSEL(w0a, w0b, j), hh, a00);
        a10 = fdot2f(WSEL(w1a, w1b, j), hh, a10);
        a01 = fdot2f(WSEL(w2a, w2b, j), hh, a01);
        a11 = fdot2f(WSEL(w3a, w3b, j), hh, a11);
        a02 = fdot2f(WSEL(w4a, w4b, j), hh, a02);
        a12 = fdot2f(WSEL(w5a, w5b, j), hh, a12);
      }
    }
    a00 += __shfl_xor(a00, 1); a00 += __shfl_xor(a00, 2);
    a10 += __shfl_xor(a10, 1); a10 += __shfl_xor(a10, 2);
    a01 += __shfl_xor(a01, 1); a01 += __shfl_xor(a01, 2);
    a11 += __shfl_xor(a11, 1); a11 += __shfl_xor(a11, 2);
    a02 += __shfl_xor(a02, 1); a02 += __shfl_xor(a02, 2);
    a12 += __shfl_xor(a12, 1); a12 += __shfl_xor(a12, 2);
    if (p == 0) {
      half2_t xrv = bch2(xr), xzv = bch2(xz), xnv = bch2(xn);
      float r0 = sigmf((float)xrv.x + a00);
      float z0 = sigmf((float)xzv.x + a01);
      float n0 = tanhf_((float)xnv.x + r0 * (a02 + bhn0));
      h0 = (1.f - z0) * n0 + z0 * h0;
      float r1 = sigmf((float)xrv.y + a10);
      float z1 = sigmf((float)xzv.y + a11);
      float n1 = tanhf_((float)xnv.y + r1 * (a12 + bhn1));
      h1 = (1.f - z1) * n1 + z1 * h1;
      uint32 ph = pack2(h0, h1);
      hb[cur ^ 1][wslice] = ph;
      xpu[(size_t)t * 384 + r] = ph;  // in-place h store (xr slot dead)
    }
    __syncthreads();
    t = tn;
  }
}

// ---------------- z_tilde + KL partials ----------------
__global__ __launch_bounds__(256) void zkl(const half_t* __restrict__ hp,  // stride 768
                                           const float* __restrict__ eps,
                                           float* __restrict__ ztil,
                                           float* __restrict__ klp) {
  const int blk = blockIdx.x, tid = threadIdx.x;
  const size_t bt = (size_t)blk * 4 + (tid >> 6);
  const int j = tid & 63;
  float mu = (float)hp[bt * 768 + j];
  float lv = (float)hp[bt * 768 + 64 + j];
  float ev = eps[bt * 64 + j];
  ztil[bt * 64 + j] = mu + __expf(0.5f * lv) * ev;
  float term = 1.f + lv - mu * mu - __expf(lv);
#pragma unroll
  for (int s = 1; s < 64; s <<= 1) term += __shfl_xor(term, s);
  __shared__ float red[4];
  if ((tid & 63) == 0) red[tid >> 6] = term;
  __syncthreads();
  if (tid == 0) klp[blk] = red[0] + red[1] + red[2] + red[3];
}

__global__ __launch_bounds__(256) void klred(const float* __restrict__ klp,
                                             float* __restrict__ out) {
  const int tid = threadIdx.x;
  float s = 0.f;
  for (int i = tid; i < 16384; i += 256) s += klp[i];
#pragma unroll
  for (int st = 1; st < 64; st <<= 1) s += __shfl_xor(s, st);
  __shared__ float red[4];
  if ((tid & 63) == 0) red[tid >> 6] = s;
  __syncthreads();
  if (tid == 0) out[0] = (red[0] + red[1] + red[2] + red[3]) * (-0.5f / 65536.f);
}

// ---------------- sequential z-scan: ONE wave per batch element ----------------
__global__ __launch_bounds__(64) void z_scan(
    const half_t* __restrict__ hp,  // pre at col offset 128, stride 768
    const float* __restrict__ zt_arr,
    const uint32* __restrict__ w1z,  // [64][64] thread-k layout
    const float* __restrict__ sw_w2, const float* __restrict__ sw_b2,
    float* __restrict__ z_out, float* __restrict__ beta_out) {
  const int b = blockIdx.x;
  const int k = threadIdx.x;  // 0..63; owns hid rows k and k+64
  uv16 z0a, z0b, z1a, z1b;    // 64 weights in named vectors
  {
#define LDZ(vec, base)                                    \
  _Pragma("unroll") for (int e = 0; e < 16; ++e) vec[e] = \
      w1z[((base) + e) * 64 + k];
    LDZ(z0a, 0); LDZ(z0b, 16); LDZ(z1a, 32); LDZ(z1b, 48);
#undef LDZ
    asm volatile("" : "+v"(z0a), "+v"(z0b), "+v"(z1a), "+v"(z1b));
  }
  const float w2k0 = sw_w2[k], w2k1 = sw_w2[k + 64], b2 = sw_b2[0];
  __shared__ uint32 zbuf[2][32];
  if (k < 32) { zbuf[0][k] = 0; zbuf[1][k] = 0; }
  __syncthreads();
  float zf = 0.f;
  const size_t bt0 = (size_t)b * T_;
  float pre0n = (float)hp[bt0 * 768 + 128 + k];
  float pre1n = (float)hp[bt0 * 768 + 192 + k];
  float ztn = zt_arr[bt0 * 64 + k];
  for (int t = 0; t < T_; ++t) {
    const int cur = t & 1;
    const float pre0 = pre0n, pre1 = pre1n, zt = ztn;
    const int tn = (t < T_ - 1) ? t + 1 : t;
    pre0n = (float)hp[(bt0 + tn) * 768 + 128 + k];
    pre1n = (float)hp[(bt0 + tn) * 768 + 192 + k];
    ztn = zt_arr[(bt0 + tn) * 64 + k];
    float a0 = 0, a1 = 0, a2 = 0, a3 = 0;
#pragma unroll
    for (int q = 0; q < 8; ++q) {
      uint4 u = *(const uint4*)&zbuf[cur][q * 4];
      const int m = q * 4;
      a0 = fdot2f(WSEL(z0a, z0b, m),     bch2(u.x), a0);
      a1 = fdot2f(WSEL(z0a, z0b, m + 1), bch2(u.y), a1);
      a0 = fdot2f(WSEL(z0a, z0b, m + 2), bch2(u.z), a0);
      a1 = fdot2f(WSEL(z0a, z0b, m + 3), bch2(u.w), a1);
      a2 = fdot2f(WSEL(z1a, z1b, m),     bch2(u.x), a2);
      a3 = fdot2f(WSEL(z1a, z1b, m + 1), bch2(u.y), a3);
      a2 = fdot2f(WSEL(z1a, z1b, m + 2), bch2(u.z), a2);
      a3 = fdot2f(WSEL(z1a, z1b, m + 3), bch2(u.w), a3);
    }
    float hid0 = fmaxf(pre0 + a0 + a1, 0.f);
    float hid1 = fmaxf(pre1 + a2 + a3, 0.f);
    float v = fmaf(hid0, w2k0, hid1 * w2k1);
#pragma unroll
    for (int s = 1; s < 64; s <<= 1) v += __shfl_xor(v, s);
    const float beta = sigmf(v + b2);
    zf = beta * zt + (1.f - beta) * zf;
    z_out[(bt0 + t) * 64 + k] = zf;
    if (k == 0) beta_out[bt0 + t] = beta;
    float zo = __shfl_xor(zf, 1);
    if ((k & 1) == 0) zbuf[cur ^ 1][k >> 1] = pack2(zf, zo);
    asm volatile("s_waitcnt lgkmcnt(0)" ::: "memory");  // single-wave LDS ordering
  }
}

extern "C" void kernel_launch(void* const* d_in, const int* in_sizes, int n_in,
                              void* d_out, int out_size, void* d_ws, size_t ws_size,
                              hipStream_t stream) {
  (void)in_sizes; (void)n_in; (void)out_size;
  const float* e_seq  = (const float*)d_in[0];
  const float* eps    = (const float*)d_in[1];
  const float* w_ih_f = (const float*)d_in[2];
  const float* w_hh_f = (const float*)d_in[3];
  const float* b_ih_f = (const float*)d_in[4];
  const float* b_hh_f = (const float*)d_in[5];
  const float* w_ih_b = (const float*)d_in[6];
  const float* w_hh_b = (const float*)d_in[7];
  const float* b_ih_b = (const float*)d_in[8];
  const float* b_hh_b = (const float*)d_in[9];
  const float* mu_w   = (const float*)d_in[10];
  const float* mu_b   = (const float*)d_in[11];
  const float* lv_w   = (const float*)d_in[12];
  const float* lv_b   = (const float*)d_in[13];
  const float* sw_w1  = (const float*)d_in[14];
  const float* sw_b1  = (const float*)d_in[15];
  const float* sw_w2  = (const float*)d_in[16];
  const float* sw_b2  = (const float*)d_in[17];

  // workspace: [0,100663296) xpf; [100663296,201326592) xpb; tail: packed weights
  const size_t NEED = 201326592 + 1924096;
  if (ws_size < NEED) return;
  char* ws = (char*)d_ws;
  half_t* xpf = (half_t*)ws;
  half_t* xpb = (half_t*)(ws + 100663296);
  half_t* hp  = xpf + 512;                      // heads cols [512,768), stride 768
  float*  ztil = (float*)(ws + 100663296);      // alias xpb (dead after head passes)
  float*  klp  = (float*)(ws + 100663296 + 16777216);
  char* wr = ws + 201326592;
  uint32* wihf  = (uint32*)(wr);                //  393216 B
  uint32* wihb  = (uint32*)(wr + 393216);       //  393216 B
  uint32* wchf  = (uint32*)(wr + 786432);       //  131072 B
  uint32* wchb  = (uint32*)(wr + 917504);       //  131072 B
  uint32* wce2  = (uint32*)(wr + 1048576);      //   65536 B
  uint32* whh2  = (uint32*)(wr + 1114112);      //  786432 B
  uint32* w1z2  = (uint32*)(wr + 1900544);      //   16384 B
  float*  biasc = (float*)(wr + 1916928);       //    1024 B
  float*  biasf = (float*)(wr + 1917952);       //    3072 B
  float*  biasb = (float*)(wr + 1921024);       //    3072 B

  pack_w<<<1879, 256, 0, stream>>>(w_ih_f, w_ih_b, mu_w, lv_w, sw_w1, w_hh_f, w_hh_b,
                                   b_ih_f, b_ih_b, b_hh_f, b_hh_b, mu_b, lv_b, sw_b1,
                                   wihf, wihb, wchf, wchb, wce2, whh2, w1z2,
                                   biasc, biasf, biasb);
  gemm_t<1, 0><<<dim3(6, 512), 256, 0, stream>>>(e_seq, 256, (const half_t*)wihf, biasf, xpf, 768, 256);
  gemm_t<1, 0><<<dim3(6, 512), 256, 0, stream>>>(e_seq, 256, (const half_t*)wihb, biasb, xpb, 768, 256);
  gru_rec<<<128, 512, 0, stream>>>((uint32*)ws, whh2, b_hh_f, b_hh_b);
  gemm_t<0, 0><<<dim3(2, 512), 256, 0, stream>>>(xpf, 768, (const half_t*)wchf, biasc, hp, 768, 256);
  gemm_t<0, 1><<<dim3(2, 512), 256, 0, stream>>>(xpb, 768, (const half_t*)wchb, nullptr, hp, 768, 256);
  gemm_t<1, 1><<<dim3(1, 512), 256, 0, stream>>>(e_seq, 256, (const half_t*)wce2, nullptr, hp + 128, 768, 256);
  zkl<<<16384, 256, 0, stream>>>(hp, eps, ztil, klp);
  klred<<<1, 256, 0, stream>>>(klp, (float*)d_out + 4194304);
  z_scan<<<64, 64, 0, stream>>>(hp, ztil, w1z2, sw_w2, sw_b2, (float*)d_out, (float*)d_out + 4194305);
}